// Round 6
// baseline (2083.502 us; speedup 1.0000x reference)
//
#include <hip/hip_runtime.h>
#include <hip/hip_bf16.h>
#include <cstddef>
#include <math.h>

// ---------------------------------------------------------------------------
// Model constants
// ---------------------------------------------------------------------------
#define S_LEN 1024
#define D_DIM 128
#define H_HEADS 8
#define DH_DIM 16
#define FF_DIM 2048
#define L_LAYERS 4
#define HID_DIM 768
#define LN_EPS 1e-5f

#define G_BLOCKS 256          // persistent grid: one barrier group
#define B_THREADS 512         // 8 waves/block
#define KSPLIT 16             // attention K-chunks (16*8*2 = 256 block units)
#define KCH (S_LEN / KSPLIT)  // 64 keys per chunk

typedef __attribute__((ext_vector_type(8))) short bf16x8;
typedef __attribute__((ext_vector_type(4))) float f32x4;

// ---------------------------------------------------------------------------
// Grid-wide barrier. Monotonic epoch counter in global memory. Release
// ordering on the increment + acquire on the spin-load, plus __threadfence()
// (agent-scope fence -> L2 writeback/inv on gfx950) for cross-XCD visibility.
// Deadlock-free: grid (256) <= guaranteed co-resident capacity (>=2 blocks/CU
// via launch_bounds(512,4), LDS ~8KB).
// ---------------------------------------------------------------------------
__device__ __forceinline__ void gbar(unsigned* cnt, unsigned* ep)
{
    __syncthreads();
    if (threadIdx.x == 0) {
        const unsigned target = ++(*ep) * (unsigned)G_BLOCKS;
        __threadfence();       // make this block's stores visible device-wide
        __hip_atomic_fetch_add(cnt, 1u, __ATOMIC_RELEASE, __HIP_MEMORY_SCOPE_AGENT);
        while (__hip_atomic_load(cnt, __ATOMIC_ACQUIRE, __HIP_MEMORY_SCOPE_AGENT) < target)
            __builtin_amdgcn_s_sleep(1);
        __threadfence();       // order subsequent loads after counter observation
    }
    __syncthreads();
}

// ---------------------------------------------------------------------------
// Wave-level MFMA tile: 16 rows x (NT*16) cols, K-contiguous bf16 operands
// loaded direct from global (proven m89/m91 fragment layout).
// ---------------------------------------------------------------------------
template<int NT>
__device__ __forceinline__ void mfma_tile(
    const __hip_bfloat16* __restrict__ A, const __hip_bfloat16* __restrict__ W,
    int K, int m0, int n0, int kbeg, int kend, int lane, f32x4* acc)
{
    const int lr = lane & 15;
    const int lk = (lane >> 4) * 8;
    const __hip_bfloat16* Ap = A + (size_t)(m0 + lr) * K + lk;
    const __hip_bfloat16* Wp = W + (size_t)(n0 + lr) * K + lk;
    for (int k = kbeg; k < kend; k += 32) {
        const bf16x8 a = *reinterpret_cast<const bf16x8*>(Ap + k);
        #pragma unroll
        for (int nt = 0; nt < NT; ++nt) {
            const bf16x8 b = *reinterpret_cast<const bf16x8*>(Wp + (size_t)nt * 16 * K + k);
            acc[nt] = __builtin_amdgcn_mfma_f32_16x16x32_bf16(a, b, acc[nt], 0, 0, 0);
        }
    }
}

// ---------------------------------------------------------------------------
// LayerNorm stage: x = LN(x + sum_p P[p] + bias)*g + b -> x (f32), x_bf.
// One wave per row (2 elems/lane); rows = blk*8 + wave; 128 blocks busy.
// ---------------------------------------------------------------------------
__device__ __forceinline__ void ln_stage(
    float* __restrict__ x, __hip_bfloat16* __restrict__ x_bf,
    const float* __restrict__ P, int nparts, const float* __restrict__ bias,
    const float* __restrict__ g, const float* __restrict__ b,
    int blk, int wave, int lane)
{
    if (blk >= 128) return;
    const int row = blk * 8 + wave;
    const int d0 = lane * 2;
    const size_t i0 = (size_t)row * D_DIM + d0;

    float v0 = x[i0], v1 = x[i0 + 1];
    for (int p = 0; p < nparts; ++p) {
        v0 += P[(size_t)p * (S_LEN * D_DIM) + i0];
        v1 += P[(size_t)p * (S_LEN * D_DIM) + i0 + 1];
    }
    v0 += bias[d0]; v1 += bias[d0 + 1];

    float s = v0 + v1;
    #pragma unroll
    for (int off = 32; off >= 1; off >>= 1) s += __shfl_xor(s, off);
    const float mu = s * (1.0f / 128.0f);

    const float q0 = v0 - mu, q1 = v1 - mu;
    float qs = q0 * q0 + q1 * q1;
    #pragma unroll
    for (int off = 32; off >= 1; off >>= 1) qs += __shfl_xor(qs, off);
    const float rs = rsqrtf(qs * (1.0f / 128.0f) + LN_EPS);

    const float r0 = q0 * rs * g[d0] + b[d0];
    const float r1 = q1 * rs * g[d0 + 1] + b[d0 + 1];
    x[i0] = r0;     x[i0 + 1] = r1;
    x_bf[i0] = __float2bfloat16(r0);
    x_bf[i0 + 1] = __float2bfloat16(r1);
}

// ---------------------------------------------------------------------------
// The megakernel: entire network, 33 grid barriers.
// ---------------------------------------------------------------------------
__global__ __launch_bounds__(B_THREADS, 4) void mega_kernel(
    const int* __restrict__ shot, const int* __restrict__ cam,
    const int* __restrict__ light, const int* __restrict__ tone,
    const int* __restrict__ rhythm, const int* __restrict__ trans,
    const float* __restrict__ motion, const float* __restrict__ focus,
    const float* __restrict__ E_shot, const float* __restrict__ E_cam,
    const float* __restrict__ E_light, const float* __restrict__ E_tone,
    const float* __restrict__ E_rhythm, const float* __restrict__ E_trans,
    const float* __restrict__ W_m1, const float* __restrict__ b_m1,
    const float* __restrict__ W_m2, const float* __restrict__ b_m2,
    const float* __restrict__ W_f, const float* __restrict__ b_f,
    const float* __restrict__ pos,
    const float* __restrict__ Wqkv, const float* __restrict__ bqkv,
    const float* __restrict__ Wo, const float* __restrict__ bo,
    const float* __restrict__ W1, const float* __restrict__ b1,
    const float* __restrict__ W2, const float* __restrict__ b2,
    const float* __restrict__ ln1_g, const float* __restrict__ ln1_b,
    const float* __restrict__ ln2_g, const float* __restrict__ ln2_b,
    const float* __restrict__ W_out, const float* __restrict__ b_out,
    float* __restrict__ ws, float* __restrict__ out)
{
    // ---- workspace carve-up (matches host layout) ----
    unsigned* cnt = (unsigned*)ws;                       // [64]
    float* x  = ws + 64;                                 // 131072 f32
    float* pm = x  + S_LEN * D_DIM;                      // 131072
    float* pl = pm + KSPLIT * H_HEADS * S_LEN;           // 131072
    float* po = pl + KSPLIT * H_HEADS * S_LEN;           // 2097152 (shared region)
    float* P  = po;                                      // alias: 2x/8x 131072 partials
    __hip_bfloat16* hbuf_bf = (__hip_bfloat16*)(P + 8 * S_LEN * D_DIM); // [1024][2048]
    __hip_bfloat16* bfb = (__hip_bfloat16*)(po + 2 * 1048576);
    __hip_bfloat16* wqkv_bf = bfb;                       // [4][384][128]
    __hip_bfloat16* wo_bf   = wqkv_bf + 196608;          // [4][128][128]
    __hip_bfloat16* w1_bf   = wo_bf   + 65536;           // [4][2048][128]
    __hip_bfloat16* w2_bf   = w1_bf   + 1048576;         // [4][128][2048]
    __hip_bfloat16* wout_bf = w2_bf   + 1048576;         // [768][128]
    __hip_bfloat16* x_bf    = wout_bf + 98304;           // [1024][128]
    __hip_bfloat16* qkv_bf  = x_bf    + 131072;          // [1024][384]
    __hip_bfloat16* attn_bf = qkv_bf  + 393216;          // [1024][128]

    __shared__ float Ks[KCH * 16];
    __shared__ float Vs[KCH * 16];

    const int blk  = blockIdx.x;
    const int tid  = threadIdx.x;
    const int wave = tid >> 6;
    const int lane = tid & 63;
    const int gw   = blk * 8 + wave;     // global wave id, 0..2047
    unsigned ep = 0;

    // ================= STAGE 0: weight conversion + embedding =================
    {
        // wconv: 614400 float4 units over 131072 threads
        for (int i = blk * B_THREADS + tid; i < 614400; i += G_BLOCKS * B_THREADS) {
            const float* src; int off4;
            if (i < 49152)       { src = Wqkv;  off4 = i; }
            else if (i < 65536)  { src = Wo;    off4 = i - 49152; }
            else if (i < 327680) { src = W1;    off4 = i - 65536; }
            else if (i < 589824) { src = W2;    off4 = i - 327680; }
            else                 { src = W_out; off4 = i - 589824; }
            const float4 v = reinterpret_cast<const float4*>(src)[off4];
            __hip_bfloat16* o = bfb + (size_t)i * 4;
            o[0] = __float2bfloat16(v.x); o[1] = __float2bfloat16(v.y);
            o[2] = __float2bfloat16(v.z); o[3] = __float2bfloat16(v.w);
        }
        // embed: one thread per (s,d); per-thread recompute of motion-MLP hidden
        const int gtid = blk * B_THREADS + tid;   // 0..131071
        const int s = gtid >> 7;
        const int d = gtid & 127;
        const float4 mp = *reinterpret_cast<const float4*>(motion + s * 4);
        const float f0 = focus[s * 2 + 0], f1 = focus[s * 2 + 1];
        float acc = b_m2[d];
        const float* w2row = W_m2 + (size_t)d * 64;
        #pragma unroll 8
        for (int k2 = 0; k2 < 64; ++k2) {
            float hk = b_m1[k2]
                     + W_m1[k2 * 4 + 0] * mp.x + W_m1[k2 * 4 + 1] * mp.y
                     + W_m1[k2 * 4 + 2] * mp.z + W_m1[k2 * 4 + 3] * mp.w;
            acc += w2row[k2] * fmaxf(hk, 0.0f);
        }
        acc += b_f[d] + W_f[d * 2 + 0] * f0 + W_f[d * 2 + 1] * f1;
        acc += E_shot  [(size_t)shot[s]   * D_DIM + d];
        acc += E_cam   [(size_t)cam[s]    * D_DIM + d];
        acc += E_light [(size_t)light[s]  * D_DIM + d];
        acc += E_tone  [(size_t)tone[s]   * D_DIM + d];
        acc += E_rhythm[(size_t)rhythm[s] * D_DIM + d];
        acc += E_trans [(size_t)trans[s]  * D_DIM + d];
        acc += pos[(size_t)s * D_DIM + d];
        x[gtid] = acc;
        x_bf[gtid] = __float2bfloat16(acc);
    }
    gbar(cnt, &ep);

    // ============================ layers ============================
    for (int li = 0; li < L_LAYERS; ++li) {
        const __hip_bfloat16* Wqkv_i = wqkv_bf + (size_t)li * 3 * D_DIM * D_DIM;
        const __hip_bfloat16* Wo_i   = wo_bf   + (size_t)li * D_DIM * D_DIM;
        const __hip_bfloat16* W1_i   = w1_bf   + (size_t)li * FF_DIM * D_DIM;
        const __hip_bfloat16* W2_i   = w2_bf   + (size_t)li * D_DIM * FF_DIM;
        const float* bqkv_i = bqkv + (size_t)li * 3 * D_DIM;
        const float* bo_i   = bo   + (size_t)li * D_DIM;
        const float* b1_i   = b1   + (size_t)li * FF_DIM;
        const float* b2_i   = b2   + (size_t)li * D_DIM;

        // ---- QKV: 768 wave units (16 rows x 32 cols each) ----
        if (gw < 768) {
            const int mt = gw / 12, nt = gw - mt * 12;
            const int m0 = mt * 16, n0 = nt * 32;
            f32x4 acc[2] = {};
            mfma_tile<2>(x_bf, Wqkv_i, 128, m0, n0, 0, 128, lane, acc);
            const int orow = m0 + (lane >> 4) * 4;
            #pragma unroll
            for (int h = 0; h < 2; ++h) {
                const int col = n0 + h * 16 + (lane & 15);
                const float bv = bqkv_i[col];
                #pragma unroll
                for (int j = 0; j < 4; ++j)
                    qkv_bf[(size_t)(orow + j) * 384 + col] =
                        __float2bfloat16(acc[h][j] + bv);
            }
        }
        gbar(cnt, &ep);

        // ---- attention partials: 256 block units (chunk, head, qhalf) ----
        {
            const int c    = blk & 15;
            const int head = (blk >> 4) & 7;
            const int qh   = blk >> 7;
            const int kbase = c * KCH;
            // stage K/V chunk: 64 rows x 16, 2 elems/thread each
            {
                const int row = tid >> 3;
                const int c2  = (tid & 7) * 2;
                const __hip_bfloat16* src =
                    qkv_bf + (size_t)(kbase + row) * 384 + head * 16 + c2;
                Ks[row * 16 + c2]     = __bfloat162float(src[128]);
                Ks[row * 16 + c2 + 1] = __bfloat162float(src[129]);
                Vs[row * 16 + c2]     = __bfloat162float(src[256]);
                Vs[row * 16 + c2 + 1] = __bfloat162float(src[257]);
            }
            const int qrow = qh * 512 + tid;
            float q[16];
            {
                const __hip_bfloat16* qp = qkv_bf + (size_t)qrow * 384 + head * 16;
                #pragma unroll
                for (int d = 0; d < 16; ++d)
                    q[d] = __bfloat162float(qp[d]) * 0.25f;
            }
            __syncthreads();

            float m = -INFINITY, l = 0.f;
            float O[16];
            #pragma unroll
            for (int d = 0; d < 16; ++d) O[d] = 0.f;

            for (int j0 = 0; j0 < KCH; j0 += 8) {
                float sv[8];
                #pragma unroll
                for (int jj = 0; jj < 8; ++jj) {
                    const float* kr = &Ks[(j0 + jj) * 16];
                    float a = 0.f;
                    #pragma unroll
                    for (int d = 0; d < 16; d += 4) {
                        const float4 kv = *reinterpret_cast<const float4*>(kr + d);
                        a += q[d] * kv.x + q[d + 1] * kv.y
                           + q[d + 2] * kv.z + q[d + 3] * kv.w;
                    }
                    sv[jj] = a;
                }
                float bm = sv[0];
                #pragma unroll
                for (int jj = 1; jj < 8; ++jj) bm = fmaxf(bm, sv[jj]);
                const float mn = fmaxf(m, bm);
                const float corr = __expf(m - mn);
                m = mn;
                l *= corr;
                #pragma unroll
                for (int d = 0; d < 16; ++d) O[d] *= corr;
                #pragma unroll
                for (int jj = 0; jj < 8; ++jj) {
                    const float p = __expf(sv[jj] - m);
                    l += p;
                    const float* vr = &Vs[(j0 + jj) * 16];
                    #pragma unroll
                    for (int d = 0; d < 16; ++d) O[d] += p * vr[d];
                }
            }
            const int pidx = ((c * H_HEADS + head) << 10) + qrow;
            pm[pidx] = m;
            pl[pidx] = l;
            #pragma unroll
            for (int d = 0; d < 16; d += 4)
                *reinterpret_cast<float4*>(&po[(size_t)pidx * 16 + d]) =
                    make_float4(O[d], O[d + 1], O[d + 2], O[d + 3]);
        }
        gbar(cnt, &ep);

        // ---- combine partials -> attn_bf: 8192 items on first 16 blocks ----
        {
            const int gid = blk * B_THREADS + tid;
            if (gid < H_HEADS * S_LEN) {
                const int head = gid >> 10;
                const int row  = gid & 1023;
                float mg = -INFINITY;
                #pragma unroll
                for (int c = 0; c < KSPLIT; ++c)
                    mg = fmaxf(mg, pm[((c * H_HEADS + head) << 10) + row]);
                float lg = 0.f;
                float O[16];
                #pragma unroll
                for (int d = 0; d < 16; ++d) O[d] = 0.f;
                #pragma unroll
                for (int c = 0; c < KSPLIT; ++c) {
                    const int pidx = ((c * H_HEADS + head) << 10) + row;
                    const float w = __expf(pm[pidx] - mg);
                    lg += pl[pidx] * w;
                    #pragma unroll
                    for (int d = 0; d < 16; d += 4) {
                        const float4 v =
                            *reinterpret_cast<const float4*>(&po[(size_t)pidx * 16 + d]);
                        O[d] += w * v.x; O[d + 1] += w * v.y;
                        O[d + 2] += w * v.z; O[d + 3] += w * v.w;
                    }
                }
                const float inv = 1.f / lg;
                __hip_bfloat16* op = attn_bf + (size_t)row * D_DIM + head * 16;
                #pragma unroll
                for (int d = 0; d < 16; ++d)
                    op[d] = __float2bfloat16(O[d] * inv);
            }
        }
        gbar(cnt, &ep);

        // ---- Wo split-K=2: 512 wave units ----
        if (gw < 512) {
            const int z  = gw & 1;
            const int nt = (gw >> 1) & 3;
            const int mt = gw >> 3;
            const int m0 = mt * 16, n0 = nt * 32;
            f32x4 acc[2] = {};
            mfma_tile<2>(attn_bf, Wo_i, 128, m0, n0, z * 64, z * 64 + 64, lane, acc);
            float* Pz = P + (size_t)z * (S_LEN * D_DIM);
            const int orow = m0 + (lane >> 4) * 4;
            #pragma unroll
            for (int h = 0; h < 2; ++h) {
                const int col = n0 + h * 16 + (lane & 15);
                #pragma unroll
                for (int j = 0; j < 4; ++j)
                    Pz[(size_t)(orow + j) * D_DIM + col] = acc[h][j];
            }
        }
        gbar(cnt, &ep);

        // ---- LN1 ----
        ln_stage(x, x_bf, P, 2, bo_i,
                 ln1_g + (size_t)li * D_DIM, ln1_b + (size_t)li * D_DIM,
                 blk, wave, lane);
        gbar(cnt, &ep);

        // ---- FF1 (+ReLU): 4096 wave units, 2 per wave ----
        for (int u = gw; u < 4096; u += 2048) {
            const int mt = u >> 6, nt = u & 63;
            const int m0 = mt * 16, n0 = nt * 32;
            f32x4 acc[2] = {};
            mfma_tile<2>(x_bf, W1_i, 128, m0, n0, 0, 128, lane, acc);
            const int orow = m0 + (lane >> 4) * 4;
            #pragma unroll
            for (int h = 0; h < 2; ++h) {
                const int col = n0 + h * 16 + (lane & 15);
                const float bv = b1_i[col];
                #pragma unroll
                for (int j = 0; j < 4; ++j)
                    hbuf_bf[(size_t)(orow + j) * FF_DIM + col] =
                        __float2bfloat16(fmaxf(acc[h][j] + bv, 0.f));
            }
        }
        gbar(cnt, &ep);

        // ---- FF2 split-K=8: 2048 wave units ----
        {
            const int z  = gw & 7;
            const int nt = (gw >> 3) & 3;
            const int mt = gw >> 5;
            const int m0 = mt * 16, n0 = nt * 32;
            f32x4 acc[2] = {};
            mfma_tile<2>(hbuf_bf, W2_i, FF_DIM, m0, n0, z * 256, z * 256 + 256, lane, acc);
            float* Pz = P + (size_t)z * (S_LEN * D_DIM);
            const int orow = m0 + (lane >> 4) * 4;
            #pragma unroll
            for (int h = 0; h < 2; ++h) {
                const int col = n0 + h * 16 + (lane & 15);
                #pragma unroll
                for (int j = 0; j < 4; ++j)
                    Pz[(size_t)(orow + j) * D_DIM + col] = acc[h][j];
            }
        }
        gbar(cnt, &ep);

        // ---- LN2 ----
        ln_stage(x, x_bf, P, 8, b2_i,
                 ln2_g + (size_t)li * D_DIM, ln2_b + (size_t)li * D_DIM,
                 blk, wave, lane);
        gbar(cnt, &ep);
    }

    // ---- output projection: 1536 wave units -> f32 out ----
    if (gw < 1536) {
        const int mt = gw / 24, nt = gw - mt * 24;
        const int m0 = mt * 16, n0 = nt * 32;
        f32x4 acc[2] = {};
        mfma_tile<2>(x_bf, wout_bf, 128, m0, n0, 0, 128, lane, acc);
        const int orow = m0 + (lane >> 4) * 4;
        #pragma unroll
        for (int h = 0; h < 2; ++h) {
            const int col = n0 + h * 16 + (lane & 15);
            const float bv = b_out[col];
            #pragma unroll
            for (int j = 0; j < 4; ++j)
                out[(size_t)(orow + j) * HID_DIM + col] = acc[h][j] + bv;
        }
    }
    // ---- boundary mask zeros (blocks 252..255 are idle in out stage) ----
    if (blk >= 252) {
        const int i = (blk - 252) * B_THREADS + tid;
        if (i < S_LEN) out[(size_t)S_LEN * HID_DIM + i] = 0.0f;
    }
}

// ---------------------------------------------------------------------------
// barrier-counter reset (runs before mega each call; keeps replays identical)
// ---------------------------------------------------------------------------
__global__ void bar_reset_kernel(unsigned* __restrict__ cnt)
{
    if (threadIdx.x < 64) cnt[threadIdx.x] = 0u;
}

// ---------------------------------------------------------------------------
// Host launch
// ---------------------------------------------------------------------------
extern "C" void kernel_launch(void* const* d_in, const int* in_sizes, int n_in,
                              void* d_out, int out_size, void* d_ws, size_t ws_size,
                              hipStream_t stream)
{
    const int*   shot    = (const int*)  d_in[0];
    const int*   cam     = (const int*)  d_in[1];
    const int*   light   = (const int*)  d_in[2];
    const int*   tone    = (const int*)  d_in[3];
    const int*   rhythm  = (const int*)  d_in[4];
    const int*   trans   = (const int*)  d_in[5];
    const float* motion  = (const float*)d_in[6];
    const float* focus   = (const float*)d_in[7];
    const float* E_shot  = (const float*)d_in[8];
    const float* E_cam   = (const float*)d_in[9];
    const float* E_light = (const float*)d_in[10];
    const float* E_tone  = (const float*)d_in[11];
    const float* E_rhyth = (const float*)d_in[12];
    const float* E_trans = (const float*)d_in[13];
    const float* W_m1    = (const float*)d_in[14];
    const float* b_m1    = (const float*)d_in[15];
    const float* W_m2    = (const float*)d_in[16];
    const float* b_m2    = (const float*)d_in[17];
    const float* W_f     = (const float*)d_in[18];
    const float* b_f     = (const float*)d_in[19];
    const float* pos     = (const float*)d_in[20];
    const float* Wqkv    = (const float*)d_in[21];
    const float* bqkv    = (const float*)d_in[22];
    const float* Wo      = (const float*)d_in[23];
    const float* bo      = (const float*)d_in[24];
    const float* W1      = (const float*)d_in[25];
    const float* b1      = (const float*)d_in[26];
    const float* W2      = (const float*)d_in[27];
    const float* b2      = (const float*)d_in[28];
    const float* ln1_g   = (const float*)d_in[29];
    const float* ln1_b   = (const float*)d_in[30];
    const float* ln2_g   = (const float*)d_in[31];
    const float* ln2_b   = (const float*)d_in[32];
    const float* W_out   = (const float*)d_in[33];
    const float* b_out   = (const float*)d_in[34];

    bar_reset_kernel<<<1, 64, 0, stream>>>((unsigned*)d_ws);

    mega_kernel<<<G_BLOCKS, B_THREADS, 0, stream>>>(
        shot, cam, light, tone, rhythm, trans, motion, focus,
        E_shot, E_cam, E_light, E_tone, E_rhyth, E_trans,
        W_m1, b_m1, W_m2, b_m2, W_f, b_f, pos,
        Wqkv, bqkv, Wo, bo, W1, b1, W2, b2,
        ln1_g, ln1_b, ln2_g, ln2_b, W_out, b_out,
        (float*)d_ws, (float*)d_out);
}

// Round 7
// 323.292 us; speedup vs baseline: 6.4446x; 6.4446x over previous
//
#include <hip/hip_runtime.h>
#include <hip/hip_bf16.h>
#include <cstddef>
#include <math.h>

// ---------------------------------------------------------------------------
// Model constants
// ---------------------------------------------------------------------------
#define S_LEN 1024
#define D_DIM 128
#define H_HEADS 8
#define FF_DIM 2048
#define L_LAYERS 4
#define HID_DIM 768
#define LN_EPS 1e-5f

#define ATT_KS 8                  // attention K-split chunks
#define ATT_KCH (S_LEN / ATT_KS)  // 128 keys per chunk

#define CH_ROWS 16                // rows owned by one chain block
#define CH_BLOCKS (S_LEN / CH_ROWS)   // 64

typedef __attribute__((ext_vector_type(8))) short bf16x8;
typedef __attribute__((ext_vector_type(4))) float f32x4;

// ---------------------------------------------------------------------------
// Wave-level MFMA tile: 16 rows x (NT*16) cols, K-contiguous bf16 operands
// loaded direct from global (proven fragment layout: A row=l&15, k=(l>>4)*8).
// ---------------------------------------------------------------------------
template<int NT>
__device__ __forceinline__ void mfma_tile(
    const __hip_bfloat16* __restrict__ A, const __hip_bfloat16* __restrict__ W,
    int K, int m0, int n0, int kbeg, int kend, int lane, f32x4* acc)
{
    const int lr = lane & 15;
    const int lk = (lane >> 4) * 8;
    const __hip_bfloat16* Ap = A + (size_t)(m0 + lr) * K + lk;
    const __hip_bfloat16* Wp = W + (size_t)(n0 + lr) * K + lk;
    for (int k = kbeg; k < kend; k += 32) {
        const bf16x8 a = *reinterpret_cast<const bf16x8*>(Ap + k);
        #pragma unroll
        for (int nt = 0; nt < NT; ++nt) {
            const bf16x8 b = *reinterpret_cast<const bf16x8*>(Wp + (size_t)nt * 16 * K + k);
            acc[nt] = __builtin_amdgcn_mfma_f32_16x16x32_bf16(a, b, acc[nt], 0, 0, 0);
        }
    }
}

// ---------------------------------------------------------------------------
// One-shot weight conversion fp32 -> bf16 (concatenated, R4-proven).
// ---------------------------------------------------------------------------
__global__ __launch_bounds__(256) void wconv_kernel(
    const float* __restrict__ Wqkv, const float* __restrict__ Wo,
    const float* __restrict__ W1, const float* __restrict__ W2,
    const float* __restrict__ Wout, __hip_bfloat16* __restrict__ dst)
{
    const int i = blockIdx.x * 256 + threadIdx.x;   // float4 index, 0..614399
    const float* src;
    int off4;
    if (i < 49152)       { src = Wqkv; off4 = i; }
    else if (i < 65536)  { src = Wo;   off4 = i - 49152; }
    else if (i < 327680) { src = W1;   off4 = i - 65536; }
    else if (i < 589824) { src = W2;   off4 = i - 327680; }
    else                 { src = Wout; off4 = i - 589824; }
    const float4 v = reinterpret_cast<const float4*>(src)[off4];
    __hip_bfloat16* o = dst + (size_t)i * 4;
    o[0] = __float2bfloat16(v.x);
    o[1] = __float2bfloat16(v.y);
    o[2] = __float2bfloat16(v.z);
    o[3] = __float2bfloat16(v.w);
}

// ---------------------------------------------------------------------------
// embed + layer-0 QKV, fused. 64 blocks x 1024 thr; block owns 16 rows.
// ---------------------------------------------------------------------------
__global__ __launch_bounds__(1024, 1) void embed_qkv_kernel(
    const int* __restrict__ shot, const int* __restrict__ cam,
    const int* __restrict__ light, const int* __restrict__ tone,
    const int* __restrict__ rhythm, const int* __restrict__ trans,
    const float* __restrict__ motion, const float* __restrict__ focus,
    const float* __restrict__ E_shot, const float* __restrict__ E_cam,
    const float* __restrict__ E_light, const float* __restrict__ E_tone,
    const float* __restrict__ E_rhythm, const float* __restrict__ E_trans,
    const float* __restrict__ W_m1, const float* __restrict__ b_m1,
    const float* __restrict__ W_m2, const float* __restrict__ b_m2,
    const float* __restrict__ W_f, const float* __restrict__ b_f,
    const float* __restrict__ pos,
    const __hip_bfloat16* __restrict__ Wqkv0, const float* __restrict__ bqkv0,
    float* __restrict__ x, __hip_bfloat16* __restrict__ x_bf,
    __hip_bfloat16* __restrict__ qkv_bf)
{
    const int blk = blockIdx.x;
    const int tid = threadIdx.x;
    const int m0  = blk * CH_ROWS;

    // ---- embed: 16 rows x 128 dims, 2 elems/thread ----
    for (int e = tid; e < CH_ROWS * D_DIM; e += 1024) {
        const int s = m0 + (e >> 7);
        const int d = e & 127;
        const float4 mp = *reinterpret_cast<const float4*>(motion + s * 4);
        const float f0 = focus[s * 2 + 0], f1 = focus[s * 2 + 1];
        float acc = b_m2[d];
        const float* w2row = W_m2 + (size_t)d * 64;
        #pragma unroll 8
        for (int k2 = 0; k2 < 64; ++k2) {
            const float hk = b_m1[k2]
                + W_m1[k2 * 4 + 0] * mp.x + W_m1[k2 * 4 + 1] * mp.y
                + W_m1[k2 * 4 + 2] * mp.z + W_m1[k2 * 4 + 3] * mp.w;
            acc += w2row[k2] * fmaxf(hk, 0.0f);
        }
        acc += b_f[d] + W_f[d * 2 + 0] * f0 + W_f[d * 2 + 1] * f1;
        acc += E_shot  [(size_t)shot[s]   * D_DIM + d];
        acc += E_cam   [(size_t)cam[s]    * D_DIM + d];
        acc += E_light [(size_t)light[s]  * D_DIM + d];
        acc += E_tone  [(size_t)tone[s]   * D_DIM + d];
        acc += E_rhythm[(size_t)rhythm[s] * D_DIM + d];
        acc += E_trans [(size_t)trans[s]  * D_DIM + d];
        acc += pos[(size_t)s * D_DIM + d];
        const size_t gi = (size_t)s * D_DIM + d;
        x[gi] = acc;
        x_bf[gi] = __float2bfloat16(acc);
    }
    __syncthreads();

    // ---- qkv layer 0: 12 units of 16x32, K=128 ----
    const int wave = tid >> 6, lane = tid & 63;
    for (int u = wave; u < 12; u += 16) {
        const int n0 = u * 32;
        f32x4 acc[2] = {};
        mfma_tile<2>(x_bf, Wqkv0, 128, m0, n0, 0, 128, lane, acc);
        const int orow = m0 + (lane >> 4) * 4;
        #pragma unroll
        for (int h = 0; h < 2; ++h) {
            const int col = n0 + h * 16 + (lane & 15);
            const float bv = bqkv0[col];
            #pragma unroll
            for (int j = 0; j < 4; ++j)
                qkv_bf[(size_t)(orow + j) * 384 + col] =
                    __float2bfloat16(acc[h][j] + bv);
        }
    }
}

// ---------------------------------------------------------------------------
// Attention split-K partials (R4-proven). grid (ATT_KS, 4, 8), 256 thr.
// ---------------------------------------------------------------------------
__global__ __launch_bounds__(256) void attn_part_kernel(
    const __hip_bfloat16* __restrict__ qkv,
    float* __restrict__ pm, float* __restrict__ pl, float* __restrict__ po)
{
    __shared__ float Ks[ATT_KCH * 16];
    __shared__ float Vs[ATT_KCH * 16];

    const int t     = threadIdx.x;
    const int chunk = blockIdx.x;
    const int qb    = blockIdx.y;
    const int head  = blockIdx.z;
    const int kbase = chunk * ATT_KCH;

    {
        const int row  = t >> 1;
        const int half = (t & 1) * 8;
        const __hip_bfloat16* src = qkv + (size_t)(kbase + row) * 384 + head * 16 + half;
        #pragma unroll
        for (int j = 0; j < 8; ++j)
            Ks[row * 16 + half + j] = __bfloat162float(src[128 + j]);
        #pragma unroll
        for (int j = 0; j < 8; ++j)
            Vs[row * 16 + half + j] = __bfloat162float(src[256 + j]);
    }

    const int qrow = qb * 256 + t;
    float q[16];
    {
        const __hip_bfloat16* qp = qkv + (size_t)qrow * 384 + head * 16;
        #pragma unroll
        for (int d = 0; d < 16; ++d)
            q[d] = __bfloat162float(qp[d]) * 0.25f;
    }
    __syncthreads();

    float m = -INFINITY, l = 0.f;
    float O[16];
    #pragma unroll
    for (int d = 0; d < 16; ++d) O[d] = 0.f;

    for (int j0 = 0; j0 < ATT_KCH; j0 += 8) {
        float sv[8];
        #pragma unroll
        for (int jj = 0; jj < 8; ++jj) {
            const float* kr = &Ks[(j0 + jj) * 16];
            float a = 0.f;
            #pragma unroll
            for (int d = 0; d < 16; d += 4) {
                const float4 kv = *reinterpret_cast<const float4*>(kr + d);
                a += q[d] * kv.x + q[d + 1] * kv.y
                   + q[d + 2] * kv.z + q[d + 3] * kv.w;
            }
            sv[jj] = a;
        }
        float bm = sv[0];
        #pragma unroll
        for (int jj = 1; jj < 8; ++jj) bm = fmaxf(bm, sv[jj]);
        const float mn = fmaxf(m, bm);
        const float corr = __expf(m - mn);
        m = mn;
        l *= corr;
        #pragma unroll
        for (int d = 0; d < 16; ++d) O[d] *= corr;
        #pragma unroll
        for (int jj = 0; jj < 8; ++jj) {
            const float p = __expf(sv[jj] - m);
            l += p;
            const float* vr = &Vs[(j0 + jj) * 16];
            #pragma unroll
            for (int d = 0; d < 16; ++d) O[d] += p * vr[d];
        }
    }

    const int pidx = ((chunk * H_HEADS + head) << 10) + qrow;
    pm[pidx] = m;
    pl[pidx] = l;
    #pragma unroll
    for (int d = 0; d < 16; d += 4)
        *reinterpret_cast<float4*>(&po[(size_t)pidx * 16 + d]) =
            make_float4(O[d], O[d + 1], O[d + 2], O[d + 3]);
}

// ---------------------------------------------------------------------------
// Row-chain: combine -> Wo -> LN1 -> FF1 -> FF2(split-K via LDS) -> LN2 ->
// next-layer QKV (or output projection if LAST). Block owns 16 rows;
// everything row-local; only block-local syncs.
// 64 blocks x 1024 thr (16 waves).
// ---------------------------------------------------------------------------
template<int LAST>
__global__ __launch_bounds__(1024, 1) void chain_kernel(
    const float* __restrict__ pm, const float* __restrict__ pl,
    const float* __restrict__ po,
    float* __restrict__ x, __hip_bfloat16* __restrict__ x_bf,
    __hip_bfloat16* __restrict__ attn_bf, __hip_bfloat16* __restrict__ hbuf_bf,
    __hip_bfloat16* __restrict__ qkv_bf,
    const __hip_bfloat16* __restrict__ Wo_i, const float* __restrict__ bo_i,
    const float* __restrict__ ln1g, const float* __restrict__ ln1b,
    const __hip_bfloat16* __restrict__ W1_i, const float* __restrict__ b1_i,
    const __hip_bfloat16* __restrict__ W2_i, const float* __restrict__ b2_i,
    const float* __restrict__ ln2g, const float* __restrict__ ln2b,
    const __hip_bfloat16* __restrict__ Wn,  const float* __restrict__ bn,
    float* __restrict__ out)
{
    __shared__ float lds_p[4][CH_ROWS][132];   // FF2 partials; [0] reused by Wo

    const int blk  = blockIdx.x;
    const int tid  = threadIdx.x;
    const int wave = tid >> 6;
    const int lane = tid & 63;
    const int m0   = blk * CH_ROWS;

    // ---- combine attention partials -> attn_bf rows ----
    {
        const int unit = tid >> 3;            // 0..127 = (rloc, head)
        const int rloc = unit >> 3;
        const int head = unit & 7;
        const int row  = m0 + rloc;
        const int d0   = (tid & 7) * 2;

        float mg = -INFINITY;
        #pragma unroll
        for (int c = 0; c < ATT_KS; ++c)
            mg = fmaxf(mg, pm[((c * H_HEADS + head) << 10) + row]);
        float lg = 0.f, O0 = 0.f, O1 = 0.f;
        #pragma unroll
        for (int c = 0; c < ATT_KS; ++c) {
            const int pidx = ((c * H_HEADS + head) << 10) + row;
            const float w = __expf(pm[pidx] - mg);
            lg += pl[pidx] * w;
            O0 += w * po[(size_t)pidx * 16 + d0];
            O1 += w * po[(size_t)pidx * 16 + d0 + 1];
        }
        const float inv = 1.f / lg;
        attn_bf[(size_t)row * D_DIM + head * 16 + d0]     = __float2bfloat16(O0 * inv);
        attn_bf[(size_t)row * D_DIM + head * 16 + d0 + 1] = __float2bfloat16(O1 * inv);
    }
    __syncthreads();

    // ---- Wo: 8 units of 16x16, K=128 -> lds_p[0] ----
    if (wave < 8) {
        const int n0 = wave * 16;
        f32x4 acc[1] = {};
        mfma_tile<1>(attn_bf, Wo_i, 128, m0, n0, 0, 128, lane, acc);
        const int orow = (lane >> 4) * 4;
        const int col  = n0 + (lane & 15);
        #pragma unroll
        for (int j = 0; j < 4; ++j)
            lds_p[0][orow + j][col] = acc[0][j];
    }
    __syncthreads();

    // ---- LN1: wave per row ----
    {
        const int rloc = wave;
        const int d0 = lane * 2;
        const size_t i0 = (size_t)(m0 + rloc) * D_DIM + d0;
        float v0 = x[i0]     + lds_p[0][rloc][d0]     + bo_i[d0];
        float v1 = x[i0 + 1] + lds_p[0][rloc][d0 + 1] + bo_i[d0 + 1];
        float s = v0 + v1;
        #pragma unroll
        for (int off = 32; off >= 1; off >>= 1) s += __shfl_xor(s, off);
        const float mu = s * (1.0f / 128.0f);
        const float q0 = v0 - mu, q1 = v1 - mu;
        float qs = q0 * q0 + q1 * q1;
        #pragma unroll
        for (int off = 32; off >= 1; off >>= 1) qs += __shfl_xor(qs, off);
        const float rs = rsqrtf(qs * (1.0f / 128.0f) + LN_EPS);
        const float r0 = q0 * rs * ln1g[d0] + ln1b[d0];
        const float r1 = q1 * rs * ln1g[d0 + 1] + ln1b[d0 + 1];
        x[i0] = r0;     x[i0 + 1] = r1;
        x_bf[i0] = __float2bfloat16(r0);
        x_bf[i0 + 1] = __float2bfloat16(r1);
    }
    __syncthreads();

    // ---- FF1 (+ReLU): 64 units of 16x32, K=128 -> hbuf ----
    for (int u = wave; u < 64; u += 16) {
        const int n0 = u * 32;
        f32x4 acc[2] = {};
        mfma_tile<2>(x_bf, W1_i, 128, m0, n0, 0, 128, lane, acc);
        const int orow = m0 + (lane >> 4) * 4;
        #pragma unroll
        for (int h = 0; h < 2; ++h) {
            const int col = n0 + h * 16 + (lane & 15);
            const float bv = b1_i[col];
            #pragma unroll
            for (int j = 0; j < 4; ++j)
                hbuf_bf[(size_t)(orow + j) * FF_DIM + col] =
                    __float2bfloat16(fmaxf(acc[h][j] + bv, 0.f));
        }
    }
    __syncthreads();

    // ---- FF2: 16 units = (4 n-tiles of 32) x (split-K=4, 512 each) ----
    {
        const int nt = wave & 3;
        const int kz = wave >> 2;
        const int n0 = nt * 32;
        f32x4 acc[2] = {};
        mfma_tile<2>(hbuf_bf, W2_i, FF_DIM, m0, n0, kz * 512, kz * 512 + 512, lane, acc);
        const int orow = (lane >> 4) * 4;
        #pragma unroll
        for (int h = 0; h < 2; ++h) {
            const int col = n0 + h * 16 + (lane & 15);
            #pragma unroll
            for (int j = 0; j < 4; ++j)
                lds_p[kz][orow + j][col] = acc[h][j];
        }
    }
    __syncthreads();

    // ---- LN2: wave per row, sum 4 partials ----
    {
        const int rloc = wave;
        const int d0 = lane * 2;
        const size_t i0 = (size_t)(m0 + rloc) * D_DIM + d0;
        float v0 = x[i0]     + b2_i[d0];
        float v1 = x[i0 + 1] + b2_i[d0 + 1];
        #pragma unroll
        for (int kz = 0; kz < 4; ++kz) {
            v0 += lds_p[kz][rloc][d0];
            v1 += lds_p[kz][rloc][d0 + 1];
        }
        float s = v0 + v1;
        #pragma unroll
        for (int off = 32; off >= 1; off >>= 1) s += __shfl_xor(s, off);
        const float mu = s * (1.0f / 128.0f);
        const float q0 = v0 - mu, q1 = v1 - mu;
        float qs = q0 * q0 + q1 * q1;
        #pragma unroll
        for (int off = 32; off >= 1; off >>= 1) qs += __shfl_xor(qs, off);
        const float rs = rsqrtf(qs * (1.0f / 128.0f) + LN_EPS);
        const float r0 = q0 * rs * ln2g[d0] + ln2b[d0];
        const float r1 = q1 * rs * ln2g[d0 + 1] + ln2b[d0 + 1];
        x[i0] = r0;     x[i0 + 1] = r1;
        x_bf[i0] = __float2bfloat16(r0);
        x_bf[i0 + 1] = __float2bfloat16(r1);
    }
    __syncthreads();

    if (!LAST) {
        // ---- next-layer QKV: 12 units of 16x32, K=128 ----
        for (int u = wave; u < 12; u += 16) {
            const int n0 = u * 32;
            f32x4 acc[2] = {};
            mfma_tile<2>(x_bf, Wn, 128, m0, n0, 0, 128, lane, acc);
            const int orow = m0 + (lane >> 4) * 4;
            #pragma unroll
            for (int h = 0; h < 2; ++h) {
                const int col = n0 + h * 16 + (lane & 15);
                const float bv = bn[col];
                #pragma unroll
                for (int j = 0; j < 4; ++j)
                    qkv_bf[(size_t)(orow + j) * 384 + col] =
                        __float2bfloat16(acc[h][j] + bv);
            }
        }
    } else {
        // ---- output projection: 24 units of 16x32, K=128 -> f32 out ----
        for (int u = wave; u < 24; u += 16) {
            const int n0 = u * 32;
            f32x4 acc[2] = {};
            mfma_tile<2>(x_bf, Wn, 128, m0, n0, 0, 128, lane, acc);
            const int orow = m0 + (lane >> 4) * 4;
            #pragma unroll
            for (int h = 0; h < 2; ++h) {
                const int col = n0 + h * 16 + (lane & 15);
                const float bv = bn[col];
                #pragma unroll
                for (int j = 0; j < 4; ++j)
                    out[(size_t)(orow + j) * HID_DIM + col] = acc[h][j] + bv;
            }
        }
        // boundary_mask zeros: block zeroes its own 16 entries
        if (tid < CH_ROWS)
            out[(size_t)S_LEN * HID_DIM + m0 + tid] = 0.0f;
    }
}

// ---------------------------------------------------------------------------
// Host launch: 10 dispatches.
// ---------------------------------------------------------------------------
extern "C" void kernel_launch(void* const* d_in, const int* in_sizes, int n_in,
                              void* d_out, int out_size, void* d_ws, size_t ws_size,
                              hipStream_t stream)
{
    const int*   shot    = (const int*)  d_in[0];
    const int*   cam     = (const int*)  d_in[1];
    const int*   light   = (const int*)  d_in[2];
    const int*   tone    = (const int*)  d_in[3];
    const int*   rhythm  = (const int*)  d_in[4];
    const int*   trans   = (const int*)  d_in[5];
    const float* motion  = (const float*)d_in[6];
    const float* focus   = (const float*)d_in[7];
    const float* E_shot  = (const float*)d_in[8];
    const float* E_cam   = (const float*)d_in[9];
    const float* E_light = (const float*)d_in[10];
    const float* E_tone  = (const float*)d_in[11];
    const float* E_rhyth = (const float*)d_in[12];
    const float* E_trans = (const float*)d_in[13];
    const float* W_m1    = (const float*)d_in[14];
    const float* b_m1    = (const float*)d_in[15];
    const float* W_m2    = (const float*)d_in[16];
    const float* b_m2    = (const float*)d_in[17];
    const float* W_f     = (const float*)d_in[18];
    const float* b_f     = (const float*)d_in[19];
    const float* pos     = (const float*)d_in[20];
    const float* Wqkv    = (const float*)d_in[21];
    const float* bqkv    = (const float*)d_in[22];
    const float* Wo      = (const float*)d_in[23];
    const float* bo      = (const float*)d_in[24];
    const float* W1      = (const float*)d_in[25];
    const float* b1      = (const float*)d_in[26];
    const float* W2      = (const float*)d_in[27];
    const float* b2      = (const float*)d_in[28];
    const float* ln1_g   = (const float*)d_in[29];
    const float* ln1_b   = (const float*)d_in[30];
    const float* ln2_g   = (const float*)d_in[31];
    const float* ln2_b   = (const float*)d_in[32];
    const float* W_out   = (const float*)d_in[33];
    const float* b_out   = (const float*)d_in[34];

    float* out = (float*)d_out;

    // workspace layout
    float* ws = (float*)d_ws;
    float* x  = ws;                                 // 131072 f32
    float* pm = x  + S_LEN * D_DIM;                 // 65536
    float* pl = pm + ATT_KS * H_HEADS * S_LEN;      // 65536
    float* po = pl + ATT_KS * H_HEADS * S_LEN;      // 1048576
    __hip_bfloat16* bfb = (__hip_bfloat16*)(po + ATT_KS * H_HEADS * S_LEN * 16);
    __hip_bfloat16* wqkv_bf = bfb;                  // [4][384][128]
    __hip_bfloat16* wo_bf   = wqkv_bf + 196608;     // [4][128][128]
    __hip_bfloat16* w1_bf   = wo_bf   + 65536;      // [4][2048][128]
    __hip_bfloat16* w2_bf   = w1_bf   + 1048576;    // [4][128][2048]
    __hip_bfloat16* wout_bf = w2_bf   + 1048576;    // [768][128]
    __hip_bfloat16* x_bf    = wout_bf + 98304;      // [1024][128]
    __hip_bfloat16* qkv_bf  = x_bf    + 131072;     // [1024][384]
    __hip_bfloat16* attn_bf = qkv_bf  + 393216;     // [1024][128]
    __hip_bfloat16* hbuf_bf = attn_bf + 131072;     // [1024][2048]

    // 1) weights -> bf16
    wconv_kernel<<<2400, 256, 0, stream>>>(Wqkv, Wo, W1, W2, W_out, bfb);

    // 2) embed + layer-0 qkv
    embed_qkv_kernel<<<CH_BLOCKS, 1024, 0, stream>>>(
        shot, cam, light, tone, rhythm, trans, motion, focus,
        E_shot, E_cam, E_light, E_tone, E_rhyth, E_trans,
        W_m1, b_m1, W_m2, b_m2, W_f, b_f, pos,
        wqkv_bf, bqkv, x, x_bf, qkv_bf);

    // 3) per layer: attention partials + row-chain
    for (int li = 0; li < L_LAYERS; ++li) {
        attn_part_kernel<<<dim3(ATT_KS, 4, H_HEADS), 256, 0, stream>>>(
            qkv_bf, pm, pl, po);

        const __hip_bfloat16* Wo_i = wo_bf + (size_t)li * D_DIM * D_DIM;
        const __hip_bfloat16* W1_i = w1_bf + (size_t)li * FF_DIM * D_DIM;
        const __hip_bfloat16* W2_i = w2_bf + (size_t)li * D_DIM * FF_DIM;
        const float* bo_i = bo + (size_t)li * D_DIM;
        const float* b1_i = b1 + (size_t)li * FF_DIM;
        const float* b2_i = b2 + (size_t)li * D_DIM;
        const float* l1g = ln1_g + (size_t)li * D_DIM;
        const float* l1b = ln1_b + (size_t)li * D_DIM;
        const float* l2g = ln2_g + (size_t)li * D_DIM;
        const float* l2b = ln2_b + (size_t)li * D_DIM;

        if (li < L_LAYERS - 1) {
            const __hip_bfloat16* Wn = wqkv_bf + (size_t)(li + 1) * 3 * D_DIM * D_DIM;
            const float* bn = bqkv + (size_t)(li + 1) * 3 * D_DIM;
            chain_kernel<0><<<CH_BLOCKS, 1024, 0, stream>>>(
                pm, pl, po, x, x_bf, attn_bf, hbuf_bf, qkv_bf,
                Wo_i, bo_i, l1g, l1b, W1_i, b1_i, W2_i, b2_i, l2g, l2b,
                Wn, bn, nullptr);
        } else {
            chain_kernel<1><<<CH_BLOCKS, 1024, 0, stream>>>(
                pm, pl, po, x, x_bf, attn_bf, hbuf_bf, qkv_bf,
                Wo_i, bo_i, l1g, l1b, W1_i, b1_i, W2_i, b2_i, l2g, l2b,
                wout_bf, b_out, out);
        }
    }
}

// Round 8
// 252.908 us; speedup vs baseline: 8.2382x; 1.2783x over previous
//
#include <hip/hip_runtime.h>
#include <hip/hip_bf16.h>
#include <cstddef>
#include <math.h>

// ---------------------------------------------------------------------------
// Model constants
// ---------------------------------------------------------------------------
#define S_LEN 1024
#define D_DIM 128
#define H_HEADS 8
#define FF_DIM 2048
#define L_LAYERS 4
#define HID_DIM 768
#define LN_EPS 1e-5f

#define ATT_KS 8                  // attention K-split chunks
#define ATT_KCH (S_LEN / ATT_KS)  // 128 keys per chunk

typedef __attribute__((ext_vector_type(8))) short bf16x8;
typedef __attribute__((ext_vector_type(4))) float f32x4;

// ---------------------------------------------------------------------------
// Wave-level MFMA tile: 16 rows x (NT*16) cols, K-contiguous bf16 operands
// loaded direct from global (proven fragment layout: A row=l&15, k=(l>>4)*8).
// Call with compile-time kbeg/kend where possible so the k-loop unrolls.
// ---------------------------------------------------------------------------
template<int NT>
__device__ __forceinline__ void mfma_tile(
    const __hip_bfloat16* __restrict__ A, const __hip_bfloat16* __restrict__ W,
    int K, int m0, int n0, int kbeg, int kend, int lane, f32x4* acc)
{
    const int lr = lane & 15;
    const int lk = (lane >> 4) * 8;
    const __hip_bfloat16* Ap = A + (size_t)(m0 + lr) * K + lk;
    const __hip_bfloat16* Wp = W + (size_t)(n0 + lr) * K + lk;
    #pragma unroll 4
    for (int k = kbeg; k < kend; k += 32) {
        const bf16x8 a = *reinterpret_cast<const bf16x8*>(Ap + k);
        #pragma unroll
        for (int nt = 0; nt < NT; ++nt) {
            const bf16x8 b = *reinterpret_cast<const bf16x8*>(Wp + (size_t)nt * 16 * K + k);
            acc[nt] = __builtin_amdgcn_mfma_f32_16x16x32_bf16(a, b, acc[nt], 0, 0, 0);
        }
    }
}

// ---------------------------------------------------------------------------
// One-shot weight conversion fp32 -> bf16 (concatenated, proven).
// ---------------------------------------------------------------------------
__global__ __launch_bounds__(256) void wconv_kernel(
    const float* __restrict__ Wqkv, const float* __restrict__ Wo,
    const float* __restrict__ W1, const float* __restrict__ W2,
    const float* __restrict__ Wout, __hip_bfloat16* __restrict__ dst)
{
    const int i = blockIdx.x * 256 + threadIdx.x;   // float4 index, 0..614399
    const float* src;
    int off4;
    if (i < 49152)       { src = Wqkv; off4 = i; }
    else if (i < 65536)  { src = Wo;   off4 = i - 49152; }
    else if (i < 327680) { src = W1;   off4 = i - 65536; }
    else if (i < 589824) { src = W2;   off4 = i - 327680; }
    else                 { src = Wout; off4 = i - 589824; }
    const float4 v = reinterpret_cast<const float4*>(src)[off4];
    __hip_bfloat16* o = dst + (size_t)i * 4;
    o[0] = __float2bfloat16(v.x);
    o[1] = __float2bfloat16(v.y);
    o[2] = __float2bfloat16(v.z);
    o[3] = __float2bfloat16(v.w);
}

// ---------------------------------------------------------------------------
// embed + layer-0 QKV, fused. 64 blocks x 1024 thr; block owns 16 rows.
// (measured fast in R7 — kept)
// ---------------------------------------------------------------------------
__global__ __launch_bounds__(1024, 1) void embed_qkv_kernel(
    const int* __restrict__ shot, const int* __restrict__ cam,
    const int* __restrict__ light, const int* __restrict__ tone,
    const int* __restrict__ rhythm, const int* __restrict__ trans,
    const float* __restrict__ motion, const float* __restrict__ focus,
    const float* __restrict__ E_shot, const float* __restrict__ E_cam,
    const float* __restrict__ E_light, const float* __restrict__ E_tone,
    const float* __restrict__ E_rhythm, const float* __restrict__ E_trans,
    const float* __restrict__ W_m1, const float* __restrict__ b_m1,
    const float* __restrict__ W_m2, const float* __restrict__ b_m2,
    const float* __restrict__ W_f, const float* __restrict__ b_f,
    const float* __restrict__ pos,
    const __hip_bfloat16* __restrict__ Wqkv0, const float* __restrict__ bqkv0,
    float* __restrict__ x, __hip_bfloat16* __restrict__ x_bf,
    __hip_bfloat16* __restrict__ qkv_bf)
{
    const int blk = blockIdx.x;
    const int tid = threadIdx.x;
    const int m0  = blk * 16;

    for (int e = tid; e < 16 * D_DIM; e += 1024) {
        const int s = m0 + (e >> 7);
        const int d = e & 127;
        const float4 mp = *reinterpret_cast<const float4*>(motion + s * 4);
        const float f0 = focus[s * 2 + 0], f1 = focus[s * 2 + 1];
        float acc = b_m2[d];
        const float* w2row = W_m2 + (size_t)d * 64;
        #pragma unroll 8
        for (int k2 = 0; k2 < 64; ++k2) {
            const float hk = b_m1[k2]
                + W_m1[k2 * 4 + 0] * mp.x + W_m1[k2 * 4 + 1] * mp.y
                + W_m1[k2 * 4 + 2] * mp.z + W_m1[k2 * 4 + 3] * mp.w;
            acc += w2row[k2] * fmaxf(hk, 0.0f);
        }
        acc += b_f[d] + W_f[d * 2 + 0] * f0 + W_f[d * 2 + 1] * f1;
        acc += E_shot  [(size_t)shot[s]   * D_DIM + d];
        acc += E_cam   [(size_t)cam[s]    * D_DIM + d];
        acc += E_light [(size_t)light[s]  * D_DIM + d];
        acc += E_tone  [(size_t)tone[s]   * D_DIM + d];
        acc += E_rhythm[(size_t)rhythm[s] * D_DIM + d];
        acc += E_trans [(size_t)trans[s]  * D_DIM + d];
        acc += pos[(size_t)s * D_DIM + d];
        const size_t gi = (size_t)s * D_DIM + d;
        x[gi] = acc;
        x_bf[gi] = __float2bfloat16(acc);
    }
    __syncthreads();

    const int wave = tid >> 6, lane = tid & 63;
    for (int u = wave; u < 12; u += 16) {
        const int n0 = u * 32;
        f32x4 acc[2] = {};
        mfma_tile<2>(x_bf, Wqkv0, 128, m0, n0, 0, 128, lane, acc);
        const int orow = m0 + (lane >> 4) * 4;
        #pragma unroll
        for (int h = 0; h < 2; ++h) {
            const int col = n0 + h * 16 + (lane & 15);
            const float bv = bqkv0[col];
            #pragma unroll
            for (int j = 0; j < 4; ++j)
                qkv_bf[(size_t)(orow + j) * 384 + col] =
                    __float2bfloat16(acc[h][j] + bv);
        }
    }
}

// ---------------------------------------------------------------------------
// Attention split-K partials (proven). grid (ATT_KS, 4, 8) = 256 blk, 256 thr.
// ---------------------------------------------------------------------------
__global__ __launch_bounds__(256) void attn_part_kernel(
    const __hip_bfloat16* __restrict__ qkv,
    float* __restrict__ pm, float* __restrict__ pl, float* __restrict__ po)
{
    __shared__ float Ks[ATT_KCH * 16];
    __shared__ float Vs[ATT_KCH * 16];

    const int t     = threadIdx.x;
    const int chunk = blockIdx.x;
    const int qb    = blockIdx.y;
    const int head  = blockIdx.z;
    const int kbase = chunk * ATT_KCH;

    {
        const int row  = t >> 1;
        const int half = (t & 1) * 8;
        const __hip_bfloat16* src = qkv + (size_t)(kbase + row) * 384 + head * 16 + half;
        #pragma unroll
        for (int j = 0; j < 8; ++j)
            Ks[row * 16 + half + j] = __bfloat162float(src[128 + j]);
        #pragma unroll
        for (int j = 0; j < 8; ++j)
            Vs[row * 16 + half + j] = __bfloat162float(src[256 + j]);
    }

    const int qrow = qb * 256 + t;
    float q[16];
    {
        const __hip_bfloat16* qp = qkv + (size_t)qrow * 384 + head * 16;
        #pragma unroll
        for (int d = 0; d < 16; ++d)
            q[d] = __bfloat162float(qp[d]) * 0.25f;
    }
    __syncthreads();

    float m = -INFINITY, l = 0.f;
    float O[16];
    #pragma unroll
    for (int d = 0; d < 16; ++d) O[d] = 0.f;

    for (int j0 = 0; j0 < ATT_KCH; j0 += 8) {
        float sv[8];
        #pragma unroll
        for (int jj = 0; jj < 8; ++jj) {
            const float* kr = &Ks[(j0 + jj) * 16];
            float a = 0.f;
            #pragma unroll
            for (int d = 0; d < 16; d += 4) {
                const float4 kv = *reinterpret_cast<const float4*>(kr + d);
                a += q[d] * kv.x + q[d + 1] * kv.y
                   + q[d + 2] * kv.z + q[d + 3] * kv.w;
            }
            sv[jj] = a;
        }
        float bm = sv[0];
        #pragma unroll
        for (int jj = 1; jj < 8; ++jj) bm = fmaxf(bm, sv[jj]);
        const float mn = fmaxf(m, bm);
        const float corr = __expf(m - mn);
        m = mn;
        l *= corr;
        #pragma unroll
        for (int d = 0; d < 16; ++d) O[d] *= corr;
        #pragma unroll
        for (int jj = 0; jj < 8; ++jj) {
            const float p = __expf(sv[jj] - m);
            l += p;
            const float* vr = &Vs[(j0 + jj) * 16];
            #pragma unroll
            for (int d = 0; d < 16; ++d) O[d] += p * vr[d];
        }
    }

    const int pidx = ((chunk * H_HEADS + head) << 10) + qrow;
    pm[pidx] = m;
    pl[pidx] = l;
    #pragma unroll
    for (int d = 0; d < 16; d += 4)
        *reinterpret_cast<float4*>(&po[(size_t)pidx * 16 + d]) =
            make_float4(O[d], O[d + 1], O[d + 2], O[d + 3]);
}

// ---------------------------------------------------------------------------
// WIDE combine: 256 blocks x 256 thr. 8192 (row,head) units x 8 lanes.
// ---------------------------------------------------------------------------
__global__ __launch_bounds__(256) void comb_kernel(
    const float* __restrict__ pm, const float* __restrict__ pl,
    const float* __restrict__ po, __hip_bfloat16* __restrict__ o)
{
    const int gid  = blockIdx.x * 256 + threadIdx.x;   // 0..65535
    const int unit = gid >> 3;                         // 0..8191
    const int head = unit >> 10;
    const int row  = unit & 1023;
    const int d0   = (gid & 7) * 2;

    float mg = -INFINITY;
    #pragma unroll
    for (int c = 0; c < ATT_KS; ++c)
        mg = fmaxf(mg, pm[((c * H_HEADS + head) << 10) + row]);

    float lg = 0.f, O0 = 0.f, O1 = 0.f;
    #pragma unroll
    for (int c = 0; c < ATT_KS; ++c) {
        const int pidx = ((c * H_HEADS + head) << 10) + row;
        const float w = __expf(pm[pidx] - mg);
        lg += pl[pidx] * w;
        O0 += w * po[(size_t)pidx * 16 + d0];
        O1 += w * po[(size_t)pidx * 16 + d0 + 1];
    }
    const float inv = 1.f / lg;
    o[(size_t)row * D_DIM + head * 16 + d0]     = __float2bfloat16(O0 * inv);
    o[(size_t)row * D_DIM + head * 16 + d0 + 1] = __float2bfloat16(O1 * inv);
}

// ---------------------------------------------------------------------------
// Wo + residual + LN1 fused. 64 blocks x 512 thr (8 waves). Block owns 16
// rows; wave w computes the 16x16 col-unit n0=w*16, K=128 (fully unrolled).
// ---------------------------------------------------------------------------
__global__ __launch_bounds__(512) void wo_ln1_kernel(
    const __hip_bfloat16* __restrict__ attn_bf,
    const __hip_bfloat16* __restrict__ Wo_i, const float* __restrict__ bo_i,
    float* __restrict__ x, __hip_bfloat16* __restrict__ x_bf,
    const float* __restrict__ g, const float* __restrict__ b)
{
    __shared__ float lds_wo[16][132];

    const int blk  = blockIdx.x;
    const int tid  = threadIdx.x;
    const int wave = tid >> 6;
    const int lane = tid & 63;
    const int m0   = blk * 16;

    {
        f32x4 acc[1] = {};
        mfma_tile<1>(attn_bf, Wo_i, 128, m0, wave * 16, 0, 128, lane, acc);
        const int orow = (lane >> 4) * 4;
        const int col  = wave * 16 + (lane & 15);
        #pragma unroll
        for (int j = 0; j < 4; ++j)
            lds_wo[orow + j][col] = acc[0][j];
    }
    __syncthreads();

    #pragma unroll
    for (int rr = 0; rr < 2; ++rr) {
        const int rloc = wave + rr * 8;
        const int d0 = lane * 2;
        const size_t i0 = (size_t)(m0 + rloc) * D_DIM + d0;
        float v0 = x[i0]     + lds_wo[rloc][d0]     + bo_i[d0];
        float v1 = x[i0 + 1] + lds_wo[rloc][d0 + 1] + bo_i[d0 + 1];
        float s = v0 + v1;
        #pragma unroll
        for (int off = 32; off >= 1; off >>= 1) s += __shfl_xor(s, off);
        const float mu = s * (1.0f / 128.0f);
        const float q0 = v0 - mu, q1 = v1 - mu;
        float qs = q0 * q0 + q1 * q1;
        #pragma unroll
        for (int off = 32; off >= 1; off >>= 1) qs += __shfl_xor(qs, off);
        const float rs = rsqrtf(qs * (1.0f / 128.0f) + LN_EPS);
        const float r0 = q0 * rs * g[d0] + b[d0];
        const float r1 = q1 * rs * g[d0 + 1] + b[d0 + 1];
        x[i0] = r0;     x[i0 + 1] = r1;
        x_bf[i0] = __float2bfloat16(r0);
        x_bf[i0 + 1] = __float2bfloat16(r1);
    }
}

// ---------------------------------------------------------------------------
// Wide MFMA GEMM (FF1): 32x64 block tile, 4 waves 2x2. grid (N/64, M/32).
// R4-proven. RELU epilogue, bf16 out.
// ---------------------------------------------------------------------------
__global__ __launch_bounds__(256) void ff1_kernel(
    const __hip_bfloat16* __restrict__ A, const __hip_bfloat16* __restrict__ W,
    const float* __restrict__ bias, __hip_bfloat16* __restrict__ C)
{
    const int t = threadIdx.x;
    const int w  = t >> 6;
    const int l  = t & 63;
    const int m0 = blockIdx.y * 32 + (w & 1) * 16;
    const int n0 = blockIdx.x * 64 + (w >> 1) * 32;

    f32x4 acc[2] = {};
    mfma_tile<2>(A, W, 128, m0, n0, 0, 128, l, acc);

    const int orow = m0 + (l >> 4) * 4;
    #pragma unroll
    for (int nt = 0; nt < 2; ++nt) {
        const int col = n0 + nt * 16 + (l & 15);
        const float bv = bias[col];
        #pragma unroll
        for (int j = 0; j < 4; ++j)
            C[(size_t)(orow + j) * FF_DIM + col] =
                __float2bfloat16(fmaxf(acc[nt][j] + bv, 0.f));
    }
}

// ---------------------------------------------------------------------------
// FF2 split-K partials: KC compile-time (256) so k-loop unrolls fully.
// grid (N/64, M/32, KS=8) = 512 blocks. P[z][M,N] f32.
// ---------------------------------------------------------------------------
template<int KC>
__global__ __launch_bounds__(256) void ff2_sk_kernel(
    const __hip_bfloat16* __restrict__ A, const __hip_bfloat16* __restrict__ W,
    float* __restrict__ P)
{
    const int t = threadIdx.x;
    const int w  = t >> 6;
    const int l  = t & 63;
    const int lr = l & 15;
    const int lk = (l >> 4) * 8;
    const int m0 = blockIdx.y * 32 + (w & 1) * 16;
    const int n0 = blockIdx.x * 64 + (w >> 1) * 32;
    const int kbeg = blockIdx.z * KC;

    f32x4 acc[2] = {};
    const __hip_bfloat16* Ap = A + (size_t)(m0 + lr) * FF_DIM + lk + kbeg;
    const __hip_bfloat16* Wp = W + (size_t)(n0 + lr) * FF_DIM + lk + kbeg;
    #pragma unroll
    for (int k = 0; k < KC; k += 32) {
        const bf16x8 a = *reinterpret_cast<const bf16x8*>(Ap + k);
        #pragma unroll
        for (int nt = 0; nt < 2; ++nt) {
            const bf16x8 bb = *reinterpret_cast<const bf16x8*>(Wp + (size_t)nt * 16 * FF_DIM + k);
            acc[nt] = __builtin_amdgcn_mfma_f32_16x16x32_bf16(a, bb, acc[nt], 0, 0, 0);
        }
    }

    float* Pz = P + (size_t)blockIdx.z * (S_LEN * D_DIM);
    const int orow = m0 + (l >> 4) * 4;
    #pragma unroll
    for (int nt = 0; nt < 2; ++nt) {
        const int col = n0 + nt * 16 + (l & 15);
        #pragma unroll
        for (int j = 0; j < 4; ++j)
            Pz[(size_t)(orow + j) * D_DIM + col] = acc[nt][j];
    }
}

// ---------------------------------------------------------------------------
// LN2 (+8 partials + bias) then next-layer QKV (or out-proj if LAST).
// 64 blocks x 512 thr; block owns 16 rows; K=128 units fully unrolled.
// ---------------------------------------------------------------------------
template<int LAST>
__global__ __launch_bounds__(512) void ln2_qkv_kernel(
    const float* __restrict__ P, const float* __restrict__ b2_i,
    float* __restrict__ x, __hip_bfloat16* __restrict__ x_bf,
    const float* __restrict__ g, const float* __restrict__ b,
    const __hip_bfloat16* __restrict__ Wn, const float* __restrict__ bn,
    __hip_bfloat16* __restrict__ qkv_bf, float* __restrict__ out)
{
    const int blk  = blockIdx.x;
    const int tid  = threadIdx.x;
    const int wave = tid >> 6;
    const int lane = tid & 63;
    const int m0   = blk * 16;

    #pragma unroll
    for (int rr = 0; rr < 2; ++rr) {
        const int rloc = wave + rr * 8;
        const int d0 = lane * 2;
        const size_t i0 = (size_t)(m0 + rloc) * D_DIM + d0;
        float v0 = x[i0]     + b2_i[d0];
        float v1 = x[i0 + 1] + b2_i[d0 + 1];
        #pragma unroll
        for (int p = 0; p < 8; ++p) {
            v0 += P[(size_t)p * (S_LEN * D_DIM) + i0];
            v1 += P[(size_t)p * (S_LEN * D_DIM) + i0 + 1];
        }
        float s = v0 + v1;
        #pragma unroll
        for (int off = 32; off >= 1; off >>= 1) s += __shfl_xor(s, off);
        const float mu = s * (1.0f / 128.0f);
        const float q0 = v0 - mu, q1 = v1 - mu;
        float qs = q0 * q0 + q1 * q1;
        #pragma unroll
        for (int off = 32; off >= 1; off >>= 1) qs += __shfl_xor(qs, off);
        const float rs = rsqrtf(qs * (1.0f / 128.0f) + LN_EPS);
        const float r0 = q0 * rs * g[d0] + b[d0];
        const float r1 = q1 * rs * g[d0 + 1] + b[d0 + 1];
        x[i0] = r0;     x[i0 + 1] = r1;
        x_bf[i0] = __float2bfloat16(r0);
        x_bf[i0 + 1] = __float2bfloat16(r1);
    }
    __syncthreads();

    if (!LAST) {
        // next-layer QKV: 12 units of 16x32 over 8 waves
        for (int u = wave; u < 12; u += 8) {
            const int n0 = u * 32;
            f32x4 acc[2] = {};
            mfma_tile<2>(x_bf, Wn, 128, m0, n0, 0, 128, lane, acc);
            const int orow = m0 + (lane >> 4) * 4;
            #pragma unroll
            for (int h = 0; h < 2; ++h) {
                const int col = n0 + h * 16 + (lane & 15);
                const float bv = bn[col];
                #pragma unroll
                for (int j = 0; j < 4; ++j)
                    qkv_bf[(size_t)(orow + j) * 384 + col] =
                        __float2bfloat16(acc[h][j] + bv);
            }
        }
    } else {
        // out-proj: 24 units of 16x32 over 8 waves -> f32 out
        for (int u = wave; u < 24; u += 8) {
            const int n0 = u * 32;
            f32x4 acc[2] = {};
            mfma_tile<2>(x_bf, Wn, 128, m0, n0, 0, 128, lane, acc);
            const int orow = m0 + (lane >> 4) * 4;
            #pragma unroll
            for (int h = 0; h < 2; ++h) {
                const int col = n0 + h * 16 + (lane & 15);
                const float bv = bn[col];
                #pragma unroll
                for (int j = 0; j < 4; ++j)
                    out[(size_t)(orow + j) * HID_DIM + col] = acc[h][j] + bv;
            }
        }
        if (tid < 16)
            out[(size_t)S_LEN * HID_DIM + m0 + tid] = 0.0f;
    }
}

// ---------------------------------------------------------------------------
// Host launch: 26 dispatches.
// ---------------------------------------------------------------------------
extern "C" void kernel_launch(void* const* d_in, const int* in_sizes, int n_in,
                              void* d_out, int out_size, void* d_ws, size_t ws_size,
                              hipStream_t stream)
{
    const int*   shot    = (const int*)  d_in[0];
    const int*   cam     = (const int*)  d_in[1];
    const int*   light   = (const int*)  d_in[2];
    const int*   tone    = (const int*)  d_in[3];
    const int*   rhythm  = (const int*)  d_in[4];
    const int*   trans   = (const int*)  d_in[5];
    const float* motion  = (const float*)d_in[6];
    const float* focus   = (const float*)d_in[7];
    const float* E_shot  = (const float*)d_in[8];
    const float* E_cam   = (const float*)d_in[9];
    const float* E_light = (const float*)d_in[10];
    const float* E_tone  = (const float*)d_in[11];
    const float* E_rhyth = (const float*)d_in[12];
    const float* E_trans = (const float*)d_in[13];
    const float* W_m1    = (const float*)d_in[14];
    const float* b_m1    = (const float*)d_in[15];
    const float* W_m2    = (const float*)d_in[16];
    const float* b_m2    = (const float*)d_in[17];
    const float* W_f     = (const float*)d_in[18];
    const float* b_f     = (const float*)d_in[19];
    const float* pos     = (const float*)d_in[20];
    const float* Wqkv    = (const float*)d_in[21];
    const float* bqkv    = (const float*)d_in[22];
    const float* Wo      = (const float*)d_in[23];
    const float* bo      = (const float*)d_in[24];
    const float* W1      = (const float*)d_in[25];
    const float* b1      = (const float*)d_in[26];
    const float* W2      = (const float*)d_in[27];
    const float* b2      = (const float*)d_in[28];
    const float* ln1_g   = (const float*)d_in[29];
    const float* ln1_b   = (const float*)d_in[30];
    const float* ln2_g   = (const float*)d_in[31];
    const float* ln2_b   = (const float*)d_in[32];
    const float* W_out   = (const float*)d_in[33];
    const float* b_out   = (const float*)d_in[34];

    float* out = (float*)d_out;

    // workspace layout
    float* ws = (float*)d_ws;
    float* x  = ws;                                 // 131072 f32
    float* pm = x  + S_LEN * D_DIM;                 // 65536
    float* pl = pm + ATT_KS * H_HEADS * S_LEN;      // 65536
    float* po = pl + ATT_KS * H_HEADS * S_LEN;      // 1048576
    float* P  = po + ATT_KS * H_HEADS * S_LEN * 16; // 1048576 (FF2 partials)
    __hip_bfloat16* bfb = (__hip_bfloat16*)(P + 8 * S_LEN * D_DIM);
    __hip_bfloat16* wqkv_bf = bfb;                  // [4][384][128]
    __hip_bfloat16* wo_bf   = wqkv_bf + 196608;     // [4][128][128]
    __hip_bfloat16* w1_bf   = wo_bf   + 65536;      // [4][2048][128]
    __hip_bfloat16* w2_bf   = w1_bf   + 1048576;    // [4][128][2048]
    __hip_bfloat16* wout_bf = w2_bf   + 1048576;    // [768][128]
    __hip_bfloat16* x_bf    = wout_bf + 98304;      // [1024][128]
    __hip_bfloat16* qkv_bf  = x_bf    + 131072;     // [1024][384]
    __hip_bfloat16* attn_bf = qkv_bf  + 393216;     // [1024][128]
    __hip_bfloat16* hbuf_bf = attn_bf + 131072;     // [1024][2048]

    // 1) weights -> bf16
    wconv_kernel<<<2400, 256, 0, stream>>>(Wqkv, Wo, W1, W2, W_out, bfb);

    // 2) embed + layer-0 qkv
    embed_qkv_kernel<<<64, 1024, 0, stream>>>(
        shot, cam, light, tone, rhythm, trans, motion, focus,
        E_shot, E_cam, E_light, E_tone, E_rhyth, E_trans,
        W_m1, b_m1, W_m2, b_m2, W_f, b_f, pos,
        wqkv_bf, bqkv, x, x_bf, qkv_bf);

    // 3) layers
    for (int li = 0; li < L_LAYERS; ++li) {
        const __hip_bfloat16* Wo_i = wo_bf + (size_t)li * D_DIM * D_DIM;
        const __hip_bfloat16* W1_i = w1_bf + (size_t)li * FF_DIM * D_DIM;
        const __hip_bfloat16* W2_i = w2_bf + (size_t)li * D_DIM * FF_DIM;
        const float* bo_i = bo + (size_t)li * D_DIM;
        const float* b1_i = b1 + (size_t)li * FF_DIM;
        const float* b2_i = b2 + (size_t)li * D_DIM;
        const float* l1g = ln1_g + (size_t)li * D_DIM;
        const float* l1b = ln1_b + (size_t)li * D_DIM;
        const float* l2g = ln2_g + (size_t)li * D_DIM;
        const float* l2b = ln2_b + (size_t)li * D_DIM;

        attn_part_kernel<<<dim3(ATT_KS, 4, H_HEADS), 256, 0, stream>>>(
            qkv_bf, pm, pl, po);

        comb_kernel<<<256, 256, 0, stream>>>(pm, pl, po, attn_bf);

        wo_ln1_kernel<<<64, 512, 0, stream>>>(
            attn_bf, Wo_i, bo_i, x, x_bf, l1g, l1b);

        ff1_kernel<<<dim3(FF_DIM / 64, S_LEN / 32), 256, 0, stream>>>(
            x_bf, W1_i, b1_i, hbuf_bf);

        ff2_sk_kernel<256><<<dim3(D_DIM / 64, S_LEN / 32, 8), 256, 0, stream>>>(
            hbuf_bf, W2_i, P);

        if (li < L_LAYERS - 1) {
            const __hip_bfloat16* Wn = wqkv_bf + (size_t)(li + 1) * 3 * D_DIM * D_DIM;
            const float* bn = bqkv + (size_t)(li + 1) * 3 * D_DIM;
            ln2_qkv_kernel<0><<<64, 512, 0, stream>>>(
                P, b2_i, x, x_bf, l2g, l2b, Wn, bn, qkv_bf, nullptr);
        } else {
            ln2_qkv_kernel<1><<<64, 512, 0, stream>>>(
                P, b2_i, x, x_bf, l2g, l2b, wout_bf, b_out, nullptr, out);
        }
    }
}